// Round 11
// baseline (215.232 us; speedup 1.0000x reference)
//
#include <hip/hip_runtime.h>
#include <hip/hip_bf16.h>
#include <stdint.h>

using bf16 = __hip_bfloat16;
typedef short short8 __attribute__((ext_vector_type(8)));
typedef short short4v __attribute__((ext_vector_type(4)));
typedef float f32x4 __attribute__((ext_vector_type(4)));

constexpr int N = 3072;
constexpr int D0 = 256;
constexpr int F1 = 128;
constexpr int F2 = 64;
constexpr int HEADS = 4;
constexpr int NW = N / 32;
constexpr float CSHIFT = 20.0f;   // softmax shift-invariance: fixed shift, no max pass

#define DI __device__ __forceinline__
DI short f2bs(float v) { bf16 b = __float2bfloat16(v); return *(short*)&b; }

// ---------------------------------------------------------------- pack adj
__global__ __launch_bounds__(256) void k_pack_adj(const int* __restrict__ adj,
                                                  uint32_t* __restrict__ bits) {
  int idx = blockIdx.x * 256 + threadIdx.x;
  unsigned long long m = __ballot(adj[idx] > 0);
  if ((threadIdx.x & 63) == 0) {
    bits[idx >> 5]       = (uint32_t)m;
    bits[(idx >> 5) + 1] = (uint32_t)(m >> 32);
  }
}

// ------------------------------------------------- convert params + x to bf16
__global__ __launch_bounds__(256) void k_cvt(const float* __restrict__ x,
                                             const float* __restrict__ W1,
                                             const float* __restrict__ lin1,
                                             const float* __restrict__ res1,
                                             const float* __restrict__ W2,
                                             const float* __restrict__ lin2,
                                             const float* __restrict__ res2,
                                             bf16* __restrict__ xb,
                                             bf16* __restrict__ W1T,
                                             bf16* __restrict__ lin1T,
                                             bf16* __restrict__ res1T,
                                             bf16* __restrict__ W2T,
                                             bf16* __restrict__ lin2T,
                                             bf16* __restrict__ res2T) {
  int t = blockIdx.y;
  int i = blockIdx.x * 256 + threadIdx.x;
  switch (t) {
    case 0:
      if (i < N * D0) xb[i] = __float2bfloat16(x[i]);
      break;
    case 1:
      if (i < HEADS * F1 * D0) { int k = i & 255; int ho = i >> 8; int h = ho >> 7, o = ho & 127;
        W1T[i] = __float2bfloat16(W1[((size_t)h * D0 + k) * F1 + o]); }
      break;
    case 2:
      if (i < F1 * HEADS * F1) { int k = i & 511; int o = i >> 9;
        lin1T[i] = __float2bfloat16(lin1[k * F1 + o]); }
      break;
    case 3:
      if (i < F1 * D0) { int k = i & 255; int o = i >> 8;
        res1T[i] = __float2bfloat16(res1[k * F1 + o]); }
      break;
    case 4:
      if (i < HEADS * F2 * F1) { int k = i & 127; int ho = i >> 7; int h = ho >> 6, o = ho & 63;
        W2T[i] = __float2bfloat16(W2[((size_t)h * F1 + k) * F2 + o]); }
      break;
    case 5:
      if (i < F2 * HEADS * F2) { int k = i & 255; int o = i >> 8;
        lin2T[i] = __float2bfloat16(lin2[k * F2 + o]); }
      break;
    case 6:
      if (i < F2 * F1) { int k = i & 127; int o = i >> 7;
        res2T[i] = __float2bfloat16(res2[k * F2 + o]); }
      break;
  }
}

// ------------------------------------------------- projection GEMM (MFMA), 16-row blocks
// Wh in MFMA B-fragment-packed order; fused src/dst GEMV via shfl + atomicAdd.
template <int K, int NOUT, int F>
__global__ __launch_bounds__(256) void k_whead_mfma(const bf16* __restrict__ A,
                                                    const bf16* __restrict__ BT,
                                                    bf16* __restrict__ BP,
                                                    const float* __restrict__ as_,
                                                    const float* __restrict__ ad_,
                                                    float* __restrict__ src,
                                                    float* __restrict__ dst) {
  int row0 = blockIdx.x * 16;
  int wid = threadIdx.x >> 6, lane = threadIdx.x & 63;
  int l15 = lane & 15, q = lane >> 4;
  int col = blockIdx.y * 64 + wid * 16 + l15;

  const bf16* aP = A + (size_t)(row0 + l15) * K + q * 8;
  const bf16* bP = BT + (size_t)col * K + q * 8;
  f32x4 acc;
#pragma unroll
  for (int r = 0; r < 4; r++) acc[r] = 0.f;
#pragma unroll
  for (int ks = 0; ks < K / 32; ks++) {
    short8 a = *(const short8*)(aP + ks * 32);
    short8 b = *(const short8*)(bP + ks * 32);
    acc = __builtin_amdgcn_mfma_f32_16x16x32_bf16(a, b, acc, 0, 0, 0);
  }

  int h  = col / F;
  int cl = col % F;
  int ct = cl >> 4;
  int jt = row0 >> 5;
  int qp = ((row0 >> 4) & 1) * 2 + (q >> 1);
  int eo = (q & 1) * 4;
  short4v w;
#pragma unroll
  for (int r = 0; r < 4; r++) w[r] = f2bs(acc[r]);
  size_t off = ((((size_t)h * (F / 16) + ct) * (N / 32) + jt) * 4 + qp) * 128 + l15 * 8 + eo;
  *(short4v*)(BP + off) = w;

  float asv = as_[col], adv = ad_[col];
#pragma unroll
  for (int r = 0; r < 4; r++) {
    float sp = acc[r] * asv, dp = acc[r] * adv;
#pragma unroll
    for (int m = 1; m < 16; m <<= 1) {
      sp += __shfl_xor(sp, m);
      dp += __shfl_xor(dp, m);
    }
    if (l15 == 0) {
      atomicAdd(&src[h * N + row0 + q * 4 + r], sp);
      atomicAdd(&dst[h * N + row0 + q * 4 + r], dp);
    }
  }
}

// ---------------- fused attention, packed-B, K-split, no main-loop barriers
// block: 32 rows x 1 head x 1 k-half; 4 waves each own 384 j's.
// Partial (unnormalized) PV and rowsum accumulate additively into f32 buffers.
template <int F>
__global__ __launch_bounds__(256, 2) void k_attn_fused(const bf16* __restrict__ BP,
                                                       const float* __restrict__ src,
                                                       const float* __restrict__ dst,
                                                       const uint32_t* __restrict__ bits,
                                                       float* __restrict__ hp_part,
                                                       float* __restrict__ rs_part) {
  constexpr int CT = F / 16;             // 8 / 4
  constexpr int CTN = CT / 4;            // 2 / 1
  constexpr int KSTEPS = 12;             // 384 j per wave
  int h    = blockIdx.y;
  int kb   = blockIdx.z;
  int row0 = blockIdx.x * 32;
  int tid = threadIdx.x, wid = tid >> 6, lane = tid & 63;
  int l15 = lane & 15, q = lane >> 4;
  int jbase = kb * (N / 2) + wid * 384;

  float src0 = src[h * N + row0 + l15];
  float src1 = src[h * N + row0 + 16 + l15];
  const float* dh = dst + h * N;
  const uint32_t* b0 = bits + (size_t)(row0 + l15) * NW;
  const uint32_t* b1 = bits + (size_t)(row0 + 16 + l15) * NW;
  const bf16* bph = BP + (size_t)h * CT * (N / 32) * 512;

  f32x4 acc0[CT], acc1[CT];
#pragma unroll
  for (int ct = 0; ct < CT; ct++)
#pragma unroll
    for (int r = 0; r < 4; r++) { acc0[ct][r] = 0.f; acc1[ct][r] = 0.f; }
  float rs0 = 0.f, rs1 = 0.f;

  for (int ks = 0; ks < KSTEPS; ks++) {
    int j0 = jbase + ks * 32;
    int jt = j0 >> 5;
    f32x4 dlo = *(const f32x4*)(dh + j0 + q * 8);
    f32x4 dhi = *(const f32x4*)(dh + j0 + q * 8 + 4);
    uint32_t m0 = (b0[jt] >> (q * 8)) & 0xffu;
    uint32_t m1 = (b1[jt] >> (q * 8)) & 0xffu;
    float pv0[8], pv1[8];
#pragma unroll
    for (int e = 0; e < 8; e++) {
      float d = e < 4 ? dlo[e] : dhi[e - 4];
      float t0 = src0 + d; t0 = fmaxf(t0, 0.2f * t0);
      float p0 = ((m0 >> e) & 1u) ? __expf(t0 - CSHIFT) : 0.f;
      rs0 += p0; pv0[e] = p0;
      float t1 = src1 + d; t1 = fmaxf(t1, 0.2f * t1);
      float p1 = ((m1 >> e) & 1u) ? __expf(t1 - CSHIFT) : 0.f;
      rs1 += p1; pv1[e] = p1;
    }
    short8 a0, a1;
#pragma unroll
    for (int e = 0; e < 8; e++) { a0[e] = f2bs(pv0[e]); a1[e] = f2bs(pv1[e]); }
#pragma unroll
    for (int ct = 0; ct < CT; ct++) {
      short8 b = *(const short8*)(bph + (((size_t)ct * (N / 32) + jt) * 64 + lane) * 8);
      acc0[ct] = __builtin_amdgcn_mfma_f32_16x16x32_bf16(a0, b, acc0[ct], 0, 0, 0);
      acc1[ct] = __builtin_amdgcn_mfma_f32_16x16x32_bf16(a1, b, acc1[ct], 0, 0, 0);
    }
  }

  rs0 += __shfl_xor(rs0, 16); rs0 += __shfl_xor(rs0, 32);
  rs1 += __shfl_xor(rs1, 16); rs1 += __shfl_xor(rs1, 32);
  if (q == 0) atomicAdd(&rs_part[((size_t)kb * HEADS + h) * N + row0 + l15], rs0);
  if (q == 1) atomicAdd(&rs_part[((size_t)kb * HEADS + h) * N + row0 + 16 + l15], rs1);

  __shared__ float red[4][64][CT * 4 + 1];
#pragma unroll
  for (int t = 0; t < 2; t++) {
    __syncthreads();
#pragma unroll
    for (int ct = 0; ct < CT; ct++)
#pragma unroll
      for (int r = 0; r < 4; r++)
        red[wid][lane][ct * 4 + r] = t ? acc1[ct][r] : acc0[ct][r];
    __syncthreads();
#pragma unroll
    for (int cc = 0; cc < CTN; cc++) {
      int ct = wid * CTN + cc;
#pragma unroll
      for (int r = 0; r < 4; r++) {
        float v = red[0][lane][ct * 4 + r] + red[1][lane][ct * 4 + r] +
                  red[2][lane][ct * 4 + r] + red[3][lane][ct * 4 + r];
        int row = row0 + t * 16 + q * 4 + r;
        hp_part[((size_t)kb * N + row) * (HEADS * F) + h * F + ct * 16 + l15] = v;
      }
    }
  }
}

// ------------------ mix GEMM (MFMA) with inline k-half combine:
// A1[row][c] = elu((hpp[0][row][c] + hpp[1][row][c]) / (rs0+rs1)); out = relu(elu(A1@B1)+A2@B2)
template <int K1, int K2, int NOUT, int F, bool F32OUT>
__global__ __launch_bounds__(256) void k_mix_mfma(const float* __restrict__ hpp,
                                                  const float* __restrict__ rs,
                                                  const bf16* __restrict__ B1T,
                                                  const bf16* __restrict__ A2,
                                                  const bf16* __restrict__ B2T,
                                                  void* __restrict__ outv) {
  int row0 = blockIdx.x * 16;
  int wid = threadIdx.x >> 6, lane = threadIdx.x & 63;
  int l15 = lane & 15, q = lane >> 4;
  int col = blockIdx.y * 64 + wid * 16 + l15;
  int row = row0 + l15;

  f32x4 acc1, acc2;
#pragma unroll
  for (int r = 0; r < 4; r++) { acc1[r] = 0.f; acc2[r] = 0.f; }

  const float* p0 = hpp + (size_t)row * K1;
  const float* p1 = hpp + ((size_t)N + row) * K1;
  const bf16* b1P = B1T + (size_t)col * K1 + q * 8;
#pragma unroll
  for (int ks = 0; ks < K1 / 32; ks++) {
    int h = (ks * 32) / F;                       // 8-elem slice never crosses a head
    float s = rs[h * N + row] + rs[(HEADS + h) * N + row];
    float inv = 1.f / s;
    int c0k = ks * 32 + q * 8;
    f32x4 x0 = *(const f32x4*)(p0 + c0k);
    f32x4 x1 = *(const f32x4*)(p0 + c0k + 4);
    f32x4 y0 = *(const f32x4*)(p1 + c0k);
    f32x4 y1 = *(const f32x4*)(p1 + c0k + 4);
    short8 a;
#pragma unroll
    for (int e = 0; e < 4; e++) {
      float v = (x0[e] + y0[e]) * inv;
      v = v > 0.f ? v : __expf(v) - 1.f;         // attention elu
      a[e] = f2bs(v);
    }
#pragma unroll
    for (int e = 0; e < 4; e++) {
      float v = (x1[e] + y1[e]) * inv;
      v = v > 0.f ? v : __expf(v) - 1.f;
      a[4 + e] = f2bs(v);
    }
    short8 b = *(const short8*)(b1P + ks * 32);
    acc1 = __builtin_amdgcn_mfma_f32_16x16x32_bf16(a, b, acc1, 0, 0, 0);
  }

  const bf16* a2P = A2 + (size_t)row * K2 + q * 8;
  const bf16* b2P = B2T + (size_t)col * K2 + q * 8;
#pragma unroll
  for (int ks = 0; ks < K2 / 32; ks++) {
    short8 a = *(const short8*)(a2P + ks * 32);
    short8 b = *(const short8*)(b2P + ks * 32);
    acc2 = __builtin_amdgcn_mfma_f32_16x16x32_bf16(a, b, acc2, 0, 0, 0);
  }

#pragma unroll
  for (int r = 0; r < 4; r++) {
    float v = acc1[r];
    v = v > 0.f ? v : __expf(v) - 1.f;           // elu on hp@lin
    v += acc2[r];
    v = v > 0.f ? v : 0.f;                       // relu
    int rw = row0 + q * 4 + r;
    if (F32OUT) ((float*)outv)[(size_t)rw * NOUT + col] = v;
    else        ((bf16*)outv)[(size_t)rw * NOUT + col] = __float2bfloat16(v);
  }
}

// ---------------------------------------------------------------- launcher
extern "C" void kernel_launch(void* const* d_in, const int* in_sizes, int n_in,
                              void* d_out, int out_size, void* d_ws, size_t ws_size,
                              hipStream_t stream) {
  const float* x    = (const float*)d_in[0];
  const int*   adj  = (const int*)d_in[1];
  const float* W1   = (const float*)d_in[2];
  const float* a1s  = (const float*)d_in[3];
  const float* a1d  = (const float*)d_in[4];
  const float* lin1 = (const float*)d_in[5];
  const float* res1 = (const float*)d_in[6];
  const float* W2   = (const float*)d_in[7];
  const float* a2s  = (const float*)d_in[8];
  const float* a2d  = (const float*)d_in[9];
  const float* lin2 = (const float*)d_in[10];
  const float* res2 = (const float*)d_in[11];
  float* out = (float*)d_out;

  char* p = (char*)d_ws;
  auto alloc = [&](size_t bytes) { void* r = (void*)p; p += (bytes + 255) & ~(size_t)255; return r; };
  uint32_t* bits = (uint32_t*)alloc((size_t)N * NW * 4);
  bf16* xb    = (bf16*)alloc((size_t)N * D0 * 2);
  bf16* W1T   = (bf16*)alloc((size_t)HEADS * F1 * D0 * 2);
  bf16* lin1T = (bf16*)alloc((size_t)F1 * HEADS * F1 * 2);
  bf16* res1T = (bf16*)alloc((size_t)F1 * D0 * 2);
  bf16* W2T   = (bf16*)alloc((size_t)HEADS * F2 * F1 * 2);
  bf16* lin2T = (bf16*)alloc((size_t)F2 * HEADS * F2 * 2);
  bf16* res2T = (bf16*)alloc((size_t)F2 * F1 * 2);
  bf16* BP1   = (bf16*)alloc((size_t)HEADS * F1 * N * 2);   // fragment-packed Wh
  bf16* BP2   = (bf16*)alloc((size_t)HEADS * F2 * N * 2);
  // zeroed region: src1,dst1,src2,dst2,rs1,rs2 (contiguous)
  float* src1 = (float*)alloc((size_t)HEADS * N * 4);
  float* dst1 = (float*)alloc((size_t)HEADS * N * 4);
  float* src2 = (float*)alloc((size_t)HEADS * N * 4);
  float* dst2 = (float*)alloc((size_t)HEADS * N * 4);
  float* rs1  = (float*)alloc((size_t)2 * HEADS * N * 4);
  float* rs2  = (float*)alloc((size_t)2 * HEADS * N * 4);
  float* hpp1 = (float*)alloc((size_t)2 * N * HEADS * F1 * 4);
  float* hpp2 = (float*)alloc((size_t)2 * N * HEADS * F2 * 4);
  bf16* h1b   = (bf16*)alloc((size_t)N * F1 * 2);

  hipMemsetAsync(src1, 0, (size_t)HEADS * N * 4 * 8, stream);  // src/dst x2 + rs x2

  k_pack_adj<<<dim3(N * N / 256), dim3(256), 0, stream>>>(adj, bits);
  k_cvt<<<dim3(N * D0 / 256, 7), dim3(256), 0, stream>>>(x, W1, lin1, res1, W2, lin2, res2,
                                                         xb, W1T, lin1T, res1T, W2T, lin2T, res2T);

  // layer 1
  k_whead_mfma<D0, HEADS * F1, F1>
      <<<dim3(N / 16, HEADS * F1 / 64), dim3(256), 0, stream>>>(xb, W1T, BP1, a1s, a1d, src1, dst1);
  k_attn_fused<F1><<<dim3(N / 32, HEADS, 2), dim3(256), 0, stream>>>(BP1, src1, dst1, bits, hpp1, rs1);
  k_mix_mfma<HEADS * F1, D0, F1, F1, false>
      <<<dim3(N / 16, F1 / 64), dim3(256), 0, stream>>>(hpp1, rs1, lin1T, xb, res1T, h1b);

  // layer 2
  k_whead_mfma<F1, HEADS * F2, F2>
      <<<dim3(N / 16, HEADS * F2 / 64), dim3(256), 0, stream>>>(h1b, W2T, BP2, a2s, a2d, src2, dst2);
  k_attn_fused<F2><<<dim3(N / 32, HEADS, 2), dim3(256), 0, stream>>>(BP2, src2, dst2, bits, hpp2, rs2);
  k_mix_mfma<HEADS * F2, F1, F2, F2, true>
      <<<dim3(N / 16, 1), dim3(256), 0, stream>>>(hpp2, rs2, lin2T, h1b, res2T, out);
}